// Round 3
// baseline (276.437 us; speedup 1.0000x reference)
//
#include <hip/hip_runtime.h>

typedef unsigned short u16;
typedef unsigned int   u32;

#define H    128
#define PAD  64    // slot row length == wave width; rows fully N-padded
#define LROW 136   // LDS row stride in u16: 128 + 8 pad (272 B, 16B-aligned)
#define MT   32    // M-tile per block (32 nodes) -> 1563 blocks, 8 waves, 4 nodes/wave

typedef __attribute__((ext_vector_type(8))) short bf16x8;
typedef __attribute__((ext_vector_type(4))) float f32x4;

__device__ __forceinline__ float bfbits2f(u32 bits16) {
  union { float f; u32 u; } c; c.u = bits16 << 16; return c.f;
}
__device__ __forceinline__ u16 f2bf(float f) {       // RNE
  union { float f; u32 u; } c; c.f = f;
  u32 u = c.u;
  return (u16)((u + 0x7fffu + ((u >> 16) & 1u)) >> 16);
}
__device__ __forceinline__ u32 fbits(float f) {
  union { float f; u32 u; } c; c.f = f; return c.u;
}

__device__ __forceinline__ void acc8(float* a, uint4 v) {
  a[0] += bfbits2f(v.x & 0xffffu); a[1] += bfbits2f(v.x >> 16);
  a[2] += bfbits2f(v.y & 0xffffu); a[3] += bfbits2f(v.y >> 16);
  a[4] += bfbits2f(v.z & 0xffffu); a[5] += bfbits2f(v.z >> 16);
  a[6] += bfbits2f(v.w & 0xffffu); a[7] += bfbits2f(v.w >> 16);
}

// cnt zero + both W hi/lo splits in one launch (independent ranges).
__global__ void k_init(int* __restrict__ cnt, int N,
                       const float* __restrict__ W1, u16* __restrict__ W1h, u16* __restrict__ W1l,
                       const float* __restrict__ W2, u16* __restrict__ W2h, u16* __restrict__ W2l) {
  int i = blockIdx.x * blockDim.x + threadIdx.x;
  if (i < N) cnt[i] = 0;
  if (i < H * H) {
    float w1 = W1[i];
    u16 h1 = f2bf(w1);
    W1h[i] = h1; W1l[i] = f2bf(w1 - bfbits2f(h1));
    float w2 = W2[i];
    u16 h2 = f2bf(w2);
    W2h[i] = h2; W2l[i] = f2bf(w2 - bfbits2f(h2));
  }
}

// slot[d*PAD + pos] = src (u16). cnt[d] ends as true in-degree.
__global__ void k_scatter(const int* __restrict__ srcA, const int* __restrict__ dstA,
                          int* __restrict__ cnt, u16* __restrict__ slot, int E, int N) {
  int e = blockIdx.x * blockDim.x + threadIdx.x;
  if (e < E) {
    int s = srcA[e], d = dstA[e];
    s = s < 0 ? 0 : (s >= N ? N - 1 : s);
    d = d < 0 ? 0 : (d >= N ? N - 1 : d);
    int pos = atomicAdd(&cnt[d], 1);
    if (pos < PAD) slot[(size_t)d * PAD + pos] = (u16)s;
  }
}

// Per node: dis = rsqrt(deg+1); xs = bf16(dis*x); slot row fully padded with
// dummy index n (zero row). Node n: zero rows of xs AND xs2 (layer-2 dummy).
__global__ __launch_bounds__(256) void k_prep_x(
    const float2* __restrict__ x, const int* __restrict__ cnt,
    float* __restrict__ dis, u32* __restrict__ xs, u32* __restrict__ xs2,
    u16* __restrict__ slot, int n) {
  int lane = threadIdx.x & 63;
  int node = blockIdx.x * 4 + (threadIdx.x >> 6);
  if (node > n) return;
  if (node == n) {                   // dummy zero rows for padded gathers
    xs [(size_t)n * 64 + lane] = 0u;
    xs2[(size_t)n * 64 + lane] = 0u;
    return;
  }
  int cv = cnt[node];
  float d = rsqrtf((float)(cv + 1));
  if (lane == 0) dis[node] = d;
  float2 v = x[(size_t)node * 64 + lane];
  xs[(size_t)node * 64 + lane] = (u32)f2bf(d * v.x) | ((u32)f2bf(d * v.y) << 16);
  int cc = cv > PAD ? PAD : cv;
  if (lane >= cc) slot[(size_t)node * PAD + lane] = (u16)n;  // full N-pad
}

// Fused layer, MT=32 nodes/block (512 thr, 8 waves), 4 nodes/wave,
// QUARTER-OWNS-NODE: 16-lane quarter q owns node n0+q entirely (16 lanes x
// uint4 = full 256 B row). One load instruction = 4 rows (1 KB), 4 nodes in
// parallel, ZERO cross-lane reduction. Slot rows preloaded transposed; edge
// loop flat + unconditional (rows fully N-padded; trip = max deg of 4 nodes),
// 8 x 1 KB loads in flight per iteration (deep MLP against ~L3 latency —
// dummy-slot overshoot adds exact zeros, bit-identical).
// Phase 2: 32x128 @ 128x128 GEMM; wave wv owns a 16-col x 32-row slice so
// each W fragment (4 hi + 4 lo, 8 KB/wave) is reused across TWO row-tiles —
// W traffic per layer = (N/32)*64KB = 100 MB. A-frags loaded per-ks inside
// the MFMA loop to stay under the launch_bounds(512,8) 64-VGPR cap.
// Same 3-term hi/lo MFMA order as before (bit-identical output).
// BF16OUT: out = bf16(dis * (y@W^T+b)) for next layer.
template <bool BF16OUT>
__global__ __launch_bounds__(512, 8) void k_layer(
    const u32* __restrict__ xs, const int* __restrict__ cntp,
    const u16* __restrict__ slot, const float* __restrict__ dis,
    const u16* __restrict__ Wh, const u16* __restrict__ Wl,
    const float* __restrict__ bias, void* __restrict__ outv, int n) {
  __shared__ u16 lyh[MT * LROW];
  __shared__ u16 lyl[MT * LROW];
  int wv = threadIdx.x >> 6;         // 0..7
  int lane = threadIdx.x & 63;
  int mBase = blockIdx.x * MT;
  int r = lane & 15, q = lane >> 4;

  // ---- phase 1 ----
  int n0 = mBase + wv * 4;
  int qb = lane & 48;                // quarter base lane
  int c  = r;                        // feature group [8c, 8c+8)
  int nq = n0 + q; nq = nq < n ? nq : n - 1;   // quarter's node (clamped tail)
  int sreg[4];
#pragma unroll
  for (int b = 0; b < 4; ++b)        // transposed slot preload, in flight
    sreg[b] = (int)slot[(size_t)nq * PAD + b * 16 + c];
  int cq = cntp[nq]; cq = cq > PAD ? PAD : cq;
  int m1 = __shfl(cq, lane ^ 16, 64); int t1 = cq > m1 ? cq : m1;
  int m2 = __shfl(t1, lane ^ 32, 64); int tmax = t1 > m2 ? t1 : m2;  // wave max

  float A[8] = {0.f,0.f,0.f,0.f,0.f,0.f,0.f,0.f};
  uint4 sv = *(const uint4*)(xs + (size_t)nq * 64 + c * 4);   // self term
  acc8(A, sv);
#pragma unroll
  for (int b = 0; b < 4; ++b) {      // compile-time b: no dynamic sreg index
    if (b * 16 >= tmax) break;       // wave-uniform
    int jend = tmax - b * 16; jend = jend > 16 ? 16 : jend;
    int sr = sreg[b];
    for (int j = 0; j < jend; j += 8) {   // 8 x 1 KB loads in flight
      int s0 = __shfl(sr, qb + j + 0, 64);
      int s1 = __shfl(sr, qb + j + 1, 64);
      int s2 = __shfl(sr, qb + j + 2, 64);
      int s3 = __shfl(sr, qb + j + 3, 64);
      int s4 = __shfl(sr, qb + j + 4, 64);
      int s5 = __shfl(sr, qb + j + 5, 64);
      int s6 = __shfl(sr, qb + j + 6, 64);
      int s7 = __shfl(sr, qb + j + 7, 64);
      uint4 v0 = *(const uint4*)(xs + (size_t)s0 * 64 + c * 4);
      uint4 v1 = *(const uint4*)(xs + (size_t)s1 * 64 + c * 4);
      uint4 v2 = *(const uint4*)(xs + (size_t)s2 * 64 + c * 4);
      uint4 v3 = *(const uint4*)(xs + (size_t)s3 * 64 + c * 4);
      uint4 v4 = *(const uint4*)(xs + (size_t)s4 * 64 + c * 4);
      uint4 v5 = *(const uint4*)(xs + (size_t)s5 * 64 + c * 4);
      uint4 v6 = *(const uint4*)(xs + (size_t)s6 * 64 + c * 4);
      uint4 v7 = *(const uint4*)(xs + (size_t)s7 * 64 + c * 4);
      acc8(A, v0);
      acc8(A, v1);
      acc8(A, v2);
      acc8(A, v3);
      acc8(A, v4);
      acc8(A, v5);
      acc8(A, v6);
      acc8(A, v7);
    }
  }
  {
    float dd = dis[nq];
    u32 u[8];
#pragma unroll
    for (int k = 0; k < 8; ++k) { A[k] *= dd; u[k] = fbits(A[k]); }
    uint4 oh, ol;
    oh.x = (u[0] >> 16) | (u[1] & 0xffff0000u);
    oh.y = (u[2] >> 16) | (u[3] & 0xffff0000u);
    oh.z = (u[4] >> 16) | (u[5] & 0xffff0000u);
    oh.w = (u[6] >> 16) | (u[7] & 0xffff0000u);
    u32 l[8];
#pragma unroll
    for (int k = 0; k < 8; ++k) l[k] = fbits(A[k] - bfbits2f(u[k] >> 16));
    ol.x = (l[0] >> 16) | (l[1] & 0xffff0000u);
    ol.y = (l[2] >> 16) | (l[3] & 0xffff0000u);
    ol.z = (l[4] >> 16) | (l[5] & 0xffff0000u);
    ol.w = (l[6] >> 16) | (l[7] & 0xffff0000u);
    int lrow = wv * 4 + q;           // 0..31; garbage rows (clamped tail) never read back
    *(uint4*)&lyh[lrow * LROW + c * 8] = oh;
    *(uint4*)&lyl[lrow * LROW + c * 8] = ol;
  }
  __syncthreads();

  // ---- phase 2: GEMM, wave wv = col-tile wv (cols 16wv..16wv+15), 2 row-tiles ----
  bf16x8 Bh[4], Bl[4];
#pragma unroll
  for (int ks = 0; ks < 4; ++ks) {
    size_t boff = (size_t)(wv * 16 + r) * H + ks * 32 + q * 8;
    Bh[ks] = *(const bf16x8*)(Wh + boff);
    Bl[ks] = *(const bf16x8*)(Wl + boff);
  }
  float bv = bias[wv * 16 + r];
  int col0 = wv * 16 + r;
#pragma unroll
  for (int rt = 0; rt < 2; ++rt) {
    f32x4 acc = (f32x4){0.f, 0.f, 0.f, 0.f};
#pragma unroll
    for (int ks = 0; ks < 4; ++ks) {     // same 3-term order as MT=16 version
      int off = (rt * 16 + r) * LROW + ks * 32 + q * 8;
      bf16x8 Ah = *(const bf16x8*)&lyh[off];
      bf16x8 Al = *(const bf16x8*)&lyl[off];
      acc = __builtin_amdgcn_mfma_f32_16x16x32_bf16(Ah, Bh[ks], acc, 0, 0, 0);
      acc = __builtin_amdgcn_mfma_f32_16x16x32_bf16(Al, Bh[ks], acc, 0, 0, 0);
      acc = __builtin_amdgcn_mfma_f32_16x16x32_bf16(Ah, Bl[ks], acc, 0, 0, 0);
    }
#pragma unroll
    for (int g = 0; g < 4; ++g) {
      int row = mBase + rt * 16 + q * 4 + g;   // C/D: col=lane&15, row=q*4+reg
      if (row < n) {
        float v = acc[g] + bv;
        if (BF16OUT) {
          float dd = dis[row];
          ((u16*)outv)[(size_t)row * H + col0] = f2bf(dd * v);
        } else {
          ((float*)outv)[(size_t)row * H + col0] = v;
        }
      }
    }
  }
}

extern "C" void kernel_launch(void* const* d_in, const int* in_sizes, int n_in,
                              void* d_out, int out_size, void* d_ws, size_t ws_size,
                              hipStream_t stream) {
  const float* x0 = (const float*)d_in[0];
  const int*   ei = (const int*)d_in[1];
  const float* W1 = (const float*)d_in[2];
  const float* b1 = (const float*)d_in[3];
  const float* W2 = (const float*)d_in[4];
  const float* b2 = (const float*)d_in[5];
  int N = in_sizes[0] / H;
  int E = in_sizes[1] / 2;
  const int* srcA = ei;
  const int* dstA = ei + E;

  char* w = (char*)d_ws;
  auto alloc = [&](size_t bytes) -> void* {
    void* p = (void*)w; w += (bytes + 255) & ~(size_t)255; return p;
  };
  int*   cnt  = (int*)  alloc((size_t)N * 4);
  float* dis  = (float*)alloc((size_t)N * 4);
  u16*   slot = (u16*)  alloc((size_t)N * PAD * 2);
  u32*   xs   = (u32*)  alloc((size_t)(N + 1) * 64 * 4); // +1: dummy zero row N
  u32*   xs2  = (u32*)  alloc((size_t)(N + 1) * 64 * 4); // layer-2 in
  u16*   W1h  = (u16*)  alloc((size_t)H * H * 2);
  u16*   W1l  = (u16*)  alloc((size_t)H * H * 2);
  u16*   W2h  = (u16*)  alloc((size_t)H * H * 2);
  u16*   W2l  = (u16*)  alloc((size_t)H * H * 2);

  k_init   <<<(N + 255) / 256, 256, 0, stream>>>(cnt, N, W1, W1h, W1l, W2, W2h, W2l);
  k_scatter<<<(E + 255) / 256, 256, 0, stream>>>(srcA, dstA, cnt, slot, E, N);
  k_prep_x <<<(N + 4) / 4, 256, 0, stream>>>((const float2*)x0, cnt, dis, xs, xs2, slot, N);

  // Layer 1: xs2 = bf16(dis * (A~*xs @ W1^T + b1))
  k_layer<true><<<(N + MT - 1) / MT, 512, 0, stream>>>(
      xs, cnt, slot, dis, W1h, W1l, b1, (void*)xs2, N);
  // Layer 2: out = A~*xs2 @ W2^T + b2 (fp32)
  k_layer<false><<<(N + MT - 1) / MT, 512, 0, stream>>>(
      xs2, cnt, slot, dis, W2h, W2l, b2, d_out, N);
}

// Round 4
// 209.941 us; speedup vs baseline: 1.3167x; 1.3167x over previous
//
#include <hip/hip_runtime.h>

typedef unsigned short u16;
typedef unsigned int   u32;

#define H    128
#define PAD  64    // slot row length == wave width; rows fully N-padded
#define LROW 136   // LDS row stride in u16: 128 + 8 pad (272 B, 16B-aligned)
#define MT   32    // M-tile per block (32 nodes) -> 1563 blocks, 8 waves, 4 nodes/wave

typedef __attribute__((ext_vector_type(8))) short bf16x8;
typedef __attribute__((ext_vector_type(4))) float f32x4;

__device__ __forceinline__ float bfbits2f(u32 bits16) {
  union { float f; u32 u; } c; c.u = bits16 << 16; return c.f;
}
__device__ __forceinline__ u16 f2bf(float f) {       // RNE
  union { float f; u32 u; } c; c.f = f;
  u32 u = c.u;
  return (u16)((u + 0x7fffu + ((u >> 16) & 1u)) >> 16);
}
__device__ __forceinline__ u32 fbits(float f) {
  union { float f; u32 u; } c; c.f = f; return c.u;
}

// cnt zero + both W hi/lo splits in one launch (independent ranges).
__global__ void k_init(int* __restrict__ cnt, int N,
                       const float* __restrict__ W1, u16* __restrict__ W1h, u16* __restrict__ W1l,
                       const float* __restrict__ W2, u16* __restrict__ W2h, u16* __restrict__ W2l) {
  int i = blockIdx.x * blockDim.x + threadIdx.x;
  if (i < N) cnt[i] = 0;
  if (i < H * H) {
    float w1 = W1[i];
    u16 h1 = f2bf(w1);
    W1h[i] = h1; W1l[i] = f2bf(w1 - bfbits2f(h1));
    float w2 = W2[i];
    u16 h2 = f2bf(w2);
    W2h[i] = h2; W2l[i] = f2bf(w2 - bfbits2f(h2));
  }
}

// slot[d*PAD + pos] = src (u16). cnt[d] ends as true in-degree.
__global__ void k_scatter(const int* __restrict__ srcA, const int* __restrict__ dstA,
                          int* __restrict__ cnt, u16* __restrict__ slot, int E, int N) {
  int e = blockIdx.x * blockDim.x + threadIdx.x;
  if (e < E) {
    int s = srcA[e], d = dstA[e];
    s = s < 0 ? 0 : (s >= N ? N - 1 : s);
    d = d < 0 ? 0 : (d >= N ? N - 1 : d);
    int pos = atomicAdd(&cnt[d], 1);
    if (pos < PAD) slot[(size_t)d * PAD + pos] = (u16)s;
  }
}

// Per node: dis = rsqrt(deg+1); xs = bf16(dis*x) in FEATURE-SLICED layout
// xs[slice][node][16 u32] (slice = 32 features = 64 B/node -> 3.2 MB/slice,
// XCD-L2-resident during the k_layer gather). Word (s,w) packs features
// 32s+2w, 32s+2w+1. slot row fully padded with dummy index n (zero row).
// Node n: zero rows of xs AND xs2 (layer-2 dummy) in all 4 slices.
__global__ __launch_bounds__(256) void k_prep_x(
    const float2* __restrict__ x, const int* __restrict__ cnt,
    float* __restrict__ dis, u32* __restrict__ xs, u32* __restrict__ xs2,
    u16* __restrict__ slot, int n) {
  int lane = threadIdx.x & 63;
  int node = blockIdx.x * 4 + (threadIdx.x >> 6);
  if (node > n) return;
  size_t idx = ((size_t)(lane >> 4) * (n + 1) + node) * 16 + (lane & 15);
  if (node == n) {                   // dummy zero rows for padded gathers
    xs [idx] = 0u;
    xs2[idx] = 0u;
    return;
  }
  int cv = cnt[node];
  float d = rsqrtf((float)(cv + 1));
  if (lane == 0) dis[node] = d;
  float2 v = x[(size_t)node * 64 + lane];   // features 2*lane, 2*lane+1
  xs[idx] = (u32)f2bf(d * v.x) | ((u32)f2bf(d * v.y) << 16);
  int cc = cv > PAD ? PAD : cv;
  if (lane >= cc) slot[(size_t)node * PAD + lane] = (u16)n;  // full N-pad
}

// Fused layer, MT=32 nodes/block (512 thr, 8 waves), 4 nodes/wave,
// QUARTER-OWNS-NODE. Phase 1 runs as 4 FEATURE-SLICE passes over the edges:
// per pass each quarter-lane owns 2 features (1 u32/row, 64 B/row-slice,
// contiguous across the 16 lanes), 8 rows of loads in flight (8 u32 payload
// regs — far under the 64-VGPR cap; the uint4 version spilled). The 3.2 MB
// slice working set is XCD-L2-resident, replacing ~6 TB/s L3 random service
// with L2 service. Each feature is accumulated self-first then in identical
// slot order -> bit-identical to the unsliced version. Dummy-slot overshoot
// adds exact zeros. Phase 2: 32x128 @ 128x128 GEMM unchanged; wave wv owns a
// 16-col x 32-row slice, W-frags (8 KB/wave) reused across two row-tiles.
// BF16OUT: out = bf16(dis * (y@W^T+b)) written in the sliced layout.
template <bool BF16OUT>
__global__ __launch_bounds__(512, 8) void k_layer(
    const u32* __restrict__ xs, const int* __restrict__ cntp,
    const u16* __restrict__ slot, const float* __restrict__ dis,
    const u16* __restrict__ Wh, const u16* __restrict__ Wl,
    const float* __restrict__ bias, void* __restrict__ outv, int n) {
  __shared__ u16 lyh[MT * LROW];
  __shared__ u16 lyl[MT * LROW];
  int wv = threadIdx.x >> 6;         // 0..7
  int lane = threadIdx.x & 63;
  int mBase = blockIdx.x * MT;
  int r = lane & 15, q = lane >> 4;

  // ---- phase 1: 4 feature-sliced passes ----
  int n0 = mBase + wv * 4;
  int qb = lane & 48;                // quarter base lane
  int c  = r;                        // u32 word in slice (features 32s+2c,+1)
  int nq = n0 + q; nq = nq < n ? nq : n - 1;   // quarter's node (clamped tail)
  int sreg[4];
#pragma unroll
  for (int b = 0; b < 4; ++b)        // transposed slot preload, in flight
    sreg[b] = (int)slot[(size_t)nq * PAD + b * 16 + c];
  int cq = cntp[nq]; cq = cq > PAD ? PAD : cq;
  int m1 = __shfl(cq, lane ^ 16, 64); int t1 = cq > m1 ? cq : m1;
  int m2 = __shfl(t1, lane ^ 32, 64); int tmax = t1 > m2 ? t1 : m2;  // wave max
  float dd = dis[nq];
  int lrow = wv * 4 + q;             // 0..31; garbage rows (tail) never read back
  size_t spitch = (size_t)(n + 1) * 16;

#pragma unroll 1
  for (int s = 0; s < 4; ++s) {
    const u32* xp = xs + (size_t)s * spitch;
    float a0 = 0.f, a1 = 0.f;
    u32 sv = xp[(size_t)nq * 16 + c];          // self term first (as before)
    a0 += bfbits2f(sv & 0xffffu); a1 += bfbits2f(sv >> 16);
#pragma unroll
    for (int b = 0; b < 4; ++b) {    // compile-time b: no dynamic sreg index
      if (b * 16 >= tmax) break;     // wave-uniform
      int jend = tmax - b * 16; jend = jend > 16 ? 16 : jend;
      int sr = sreg[b];
      for (int j = 0; j < jend; j += 8) {   // 8 row-loads in flight (u32 each)
        int s0 = __shfl(sr, qb + j + 0, 64);
        int s1 = __shfl(sr, qb + j + 1, 64);
        int s2 = __shfl(sr, qb + j + 2, 64);
        int s3 = __shfl(sr, qb + j + 3, 64);
        int s4 = __shfl(sr, qb + j + 4, 64);
        int s5 = __shfl(sr, qb + j + 5, 64);
        int s6 = __shfl(sr, qb + j + 6, 64);
        int s7 = __shfl(sr, qb + j + 7, 64);
        u32 e0 = xp[(size_t)s0 * 16 + c];
        u32 e1 = xp[(size_t)s1 * 16 + c];
        u32 e2 = xp[(size_t)s2 * 16 + c];
        u32 e3 = xp[(size_t)s3 * 16 + c];
        u32 e4 = xp[(size_t)s4 * 16 + c];
        u32 e5 = xp[(size_t)s5 * 16 + c];
        u32 e6 = xp[(size_t)s6 * 16 + c];
        u32 e7 = xp[(size_t)s7 * 16 + c];
        a0 += bfbits2f(e0 & 0xffffu); a1 += bfbits2f(e0 >> 16);
        a0 += bfbits2f(e1 & 0xffffu); a1 += bfbits2f(e1 >> 16);
        a0 += bfbits2f(e2 & 0xffffu); a1 += bfbits2f(e2 >> 16);
        a0 += bfbits2f(e3 & 0xffffu); a1 += bfbits2f(e3 >> 16);
        a0 += bfbits2f(e4 & 0xffffu); a1 += bfbits2f(e4 >> 16);
        a0 += bfbits2f(e5 & 0xffffu); a1 += bfbits2f(e5 >> 16);
        a0 += bfbits2f(e6 & 0xffffu); a1 += bfbits2f(e6 >> 16);
        a0 += bfbits2f(e7 & 0xffffu); a1 += bfbits2f(e7 >> 16);
      }
    }
    float f0 = a0 * dd, f1 = a1 * dd;          // same per-feature op order
    u32 u0 = fbits(f0), u1 = fbits(f1);
    u32 l0 = fbits(f0 - bfbits2f(u0 >> 16));
    u32 l1 = fbits(f1 - bfbits2f(u1 >> 16));
    ((u32*)lyh)[lrow * (LROW / 2) + s * 16 + c] = (u0 >> 16) | (u1 & 0xffff0000u);
    ((u32*)lyl)[lrow * (LROW / 2) + s * 16 + c] = (l0 >> 16) | (l1 & 0xffff0000u);
  }
  __syncthreads();

  // ---- phase 2: GEMM, wave wv = col-tile wv (cols 16wv..16wv+15), 2 row-tiles ----
  bf16x8 Bh[4], Bl[4];
#pragma unroll
  for (int ks = 0; ks < 4; ++ks) {
    size_t boff = (size_t)(wv * 16 + r) * H + ks * 32 + q * 8;
    Bh[ks] = *(const bf16x8*)(Wh + boff);
    Bl[ks] = *(const bf16x8*)(Wl + boff);
  }
  float bv = bias[wv * 16 + r];
  int col0 = wv * 16 + r;
#pragma unroll
  for (int rt = 0; rt < 2; ++rt) {
    f32x4 acc = (f32x4){0.f, 0.f, 0.f, 0.f};
#pragma unroll
    for (int ks = 0; ks < 4; ++ks) {     // same 3-term hi/lo order as before
      int off = (rt * 16 + r) * LROW + ks * 32 + q * 8;
      bf16x8 Ah = *(const bf16x8*)&lyh[off];
      bf16x8 Al = *(const bf16x8*)&lyl[off];
      acc = __builtin_amdgcn_mfma_f32_16x16x32_bf16(Ah, Bh[ks], acc, 0, 0, 0);
      acc = __builtin_amdgcn_mfma_f32_16x16x32_bf16(Al, Bh[ks], acc, 0, 0, 0);
      acc = __builtin_amdgcn_mfma_f32_16x16x32_bf16(Ah, Bl[ks], acc, 0, 0, 0);
    }
#pragma unroll
    for (int g = 0; g < 4; ++g) {
      int row = mBase + rt * 16 + q * 4 + g;   // C/D: col=lane&15, row=q*4+reg
      if (row < n) {
        float v = acc[g] + bv;
        if (BF16OUT) {
          float d2 = dis[row];
          // sliced layout: slice col0>>5, u16 pos col0&31 within 64 B node row
          ((u16*)outv)[((size_t)(col0 >> 5) * (n + 1) + row) * 32 + (col0 & 31)]
              = f2bf(d2 * v);
        } else {
          ((float*)outv)[(size_t)row * H + col0] = v;   // canonical fp32 out
        }
      }
    }
  }
}

extern "C" void kernel_launch(void* const* d_in, const int* in_sizes, int n_in,
                              void* d_out, int out_size, void* d_ws, size_t ws_size,
                              hipStream_t stream) {
  const float* x0 = (const float*)d_in[0];
  const int*   ei = (const int*)d_in[1];
  const float* W1 = (const float*)d_in[2];
  const float* b1 = (const float*)d_in[3];
  const float* W2 = (const float*)d_in[4];
  const float* b2 = (const float*)d_in[5];
  int N = in_sizes[0] / H;
  int E = in_sizes[1] / 2;
  const int* srcA = ei;
  const int* dstA = ei + E;

  char* w = (char*)d_ws;
  auto alloc = [&](size_t bytes) -> void* {
    void* p = (void*)w; w += (bytes + 255) & ~(size_t)255; return p;
  };
  int*   cnt  = (int*)  alloc((size_t)N * 4);
  float* dis  = (float*)alloc((size_t)N * 4);
  u16*   slot = (u16*)  alloc((size_t)N * PAD * 2);
  u32*   xs   = (u32*)  alloc((size_t)(N + 1) * 64 * 4); // 4 slices x (N+1) x 64 B
  u32*   xs2  = (u32*)  alloc((size_t)(N + 1) * 64 * 4); // layer-2 in (sliced)
  u16*   W1h  = (u16*)  alloc((size_t)H * H * 2);
  u16*   W1l  = (u16*)  alloc((size_t)H * H * 2);
  u16*   W2h  = (u16*)  alloc((size_t)H * H * 2);
  u16*   W2l  = (u16*)  alloc((size_t)H * H * 2);

  k_init   <<<(N + 255) / 256, 256, 0, stream>>>(cnt, N, W1, W1h, W1l, W2, W2h, W2l);
  k_scatter<<<(E + 255) / 256, 256, 0, stream>>>(srcA, dstA, cnt, slot, E, N);
  k_prep_x <<<(N + 4) / 4, 256, 0, stream>>>((const float2*)x0, cnt, dis, xs, xs2, slot, N);

  // Layer 1: xs2 = bf16(dis * (A~*xs @ W1^T + b1))
  k_layer<true><<<(N + MT - 1) / MT, 512, 0, stream>>>(
      xs, cnt, slot, dis, W1h, W1l, b1, (void*)xs2, N);
  // Layer 2: out = A~*xs2 @ W2^T + b2 (fp32)
  k_layer<false><<<(N + MT - 1) / MT, 512, 0, stream>>>(
      xs2, cnt, slot, dis, W2h, W2l, b2, d_out, N);
}

// Round 6
// 192.296 us; speedup vs baseline: 1.4376x; 1.0918x over previous
//
#include <hip/hip_runtime.h>

typedef unsigned short u16;
typedef unsigned int   u32;

#define H    128
#define PAD  64    // slot row length == wave width; rows fully N-padded
#define LROW 136   // LDS row stride in u16: 128 + 8 pad (272 B, 16B-aligned)
#define MT   64    // M-tile per block (64 nodes) -> 782 blocks, 8 waves, 8 nodes/wave

typedef __attribute__((ext_vector_type(8))) short bf16x8;
typedef __attribute__((ext_vector_type(4))) float f32x4;

__device__ __forceinline__ float bfbits2f(u32 bits16) {
  union { float f; u32 u; } c; c.u = bits16 << 16; return c.f;
}
__device__ __forceinline__ u16 f2bf(float f) {       // RNE
  union { float f; u32 u; } c; c.f = f;
  u32 u = c.u;
  return (u16)((u + 0x7fffu + ((u >> 16) & 1u)) >> 16);
}
__device__ __forceinline__ u32 fbits(float f) {
  union { float f; u32 u; } c; c.f = f; return c.u;
}

__device__ __forceinline__ void acc8(float* a, uint4 v) {
  a[0] += bfbits2f(v.x & 0xffffu); a[1] += bfbits2f(v.x >> 16);
  a[2] += bfbits2f(v.y & 0xffffu); a[3] += bfbits2f(v.y >> 16);
  a[4] += bfbits2f(v.z & 0xffffu); a[5] += bfbits2f(v.z >> 16);
  a[6] += bfbits2f(v.w & 0xffffu); a[7] += bfbits2f(v.w >> 16);
}

// cnt zero + both W hi/lo splits in one launch (independent ranges).
__global__ void k_init(int* __restrict__ cnt, int N,
                       const float* __restrict__ W1, u16* __restrict__ W1h, u16* __restrict__ W1l,
                       const float* __restrict__ W2, u16* __restrict__ W2h, u16* __restrict__ W2l) {
  int i = blockIdx.x * blockDim.x + threadIdx.x;
  if (i < N) cnt[i] = 0;
  if (i < H * H) {
    float w1 = W1[i];
    u16 h1 = f2bf(w1);
    W1h[i] = h1; W1l[i] = f2bf(w1 - bfbits2f(h1));
    float w2 = W2[i];
    u16 h2 = f2bf(w2);
    W2h[i] = h2; W2l[i] = f2bf(w2 - bfbits2f(h2));
  }
}

// slot[d*PAD + pos] = src (u16). cnt[d] ends as true in-degree.
__global__ void k_scatter(const int* __restrict__ srcA, const int* __restrict__ dstA,
                          int* __restrict__ cnt, u16* __restrict__ slot, int E, int N) {
  int e = blockIdx.x * blockDim.x + threadIdx.x;
  if (e < E) {
    int s = srcA[e], d = dstA[e];
    s = s < 0 ? 0 : (s >= N ? N - 1 : s);
    d = d < 0 ? 0 : (d >= N ? N - 1 : d);
    int pos = atomicAdd(&cnt[d], 1);
    if (pos < PAD) slot[(size_t)d * PAD + pos] = (u16)s;
  }
}

// Per node: dis = rsqrt(deg+1); xs = bf16(dis*x) interleaved [node][64 u32];
// slot row fully padded with dummy index n (zero row). Node n: zero rows of
// xs AND xs2 (layer-2 dummy).
__global__ __launch_bounds__(256) void k_prep_x(
    const float2* __restrict__ x, const int* __restrict__ cnt,
    float* __restrict__ dis, u32* __restrict__ xs, u32* __restrict__ xs2,
    u16* __restrict__ slot, int n) {
  int lane = threadIdx.x & 63;
  int node = blockIdx.x * 4 + (threadIdx.x >> 6);
  if (node > n) return;
  if (node == n) {                   // dummy zero rows for padded gathers
    xs [(size_t)n * 64 + lane] = 0u;
    xs2[(size_t)n * 64 + lane] = 0u;
    return;
  }
  int cv = cnt[node];
  float d = rsqrtf((float)(cv + 1));
  if (lane == 0) dis[node] = d;
  float2 v = x[(size_t)node * 64 + lane];
  xs[(size_t)node * 64 + lane] = (u32)f2bf(d * v.x) | ((u32)f2bf(d * v.y) << 16);
  int cc = cv > PAD ? PAD : cv;
  if (lane >= cc) slot[(size_t)node * PAD + lane] = (u16)n;  // full N-pad
}

// Fused layer, MT=64 nodes/block (512 thr, 8 waves), 8 nodes/wave processed
// as TWO sequential 4-node batches (per-batch math identical to the MT=32
// version -> bit-identical output). QUARTER-OWNS-NODE: 16-lane quarter q owns
// one node entirely (16 lanes x uint4 = full 256 B row). One load instruction
// = 4 rows (1 KB), 4 nodes in parallel, ZERO cross-lane reduction. Slot rows
// preloaded transposed; edge loop flat + unconditional (rows fully N-padded;
// trip = max deg of the batch's 4 nodes), 4 x 1 KB loads in flight (8-deep
// uint4 spilled — round-3 lesson).
// Phase 2: 64x128 @ 128x128 GEMM; wave wv owns a 16-col x 64-row slice so
// each W fragment set (4 hi + 4 lo, 8 KB/wave) is reused across FOUR
// row-tiles — W traffic per layer = (N/64)*64KB = 50 MB (half of MT=32).
// A-frags loaded per-ks inside the MFMA loop (64-VGPR cap). Same 3-term
// hi/lo MFMA order as before (bit-identical output).
// BF16OUT: out = bf16(dis * (y@W^T+b)) for next layer.
template <bool BF16OUT>
__global__ __launch_bounds__(512, 8) void k_layer(
    const u32* __restrict__ xs, const int* __restrict__ cntp,
    const u16* __restrict__ slot, const float* __restrict__ dis,
    const u16* __restrict__ Wh, const u16* __restrict__ Wl,
    const float* __restrict__ bias, void* __restrict__ outv, int n) {
  __shared__ u16 lyh[MT * LROW];
  __shared__ u16 lyl[MT * LROW];
  int wv = threadIdx.x >> 6;         // 0..7
  int lane = threadIdx.x & 63;
  int mBase = blockIdx.x * MT;
  int r = lane & 15, q = lane >> 4;
  int qb = lane & 48;                // quarter base lane
  int c  = r;                        // feature group [8c, 8c+8)

  // ---- phase 1: two 4-node batches per wave ----
#pragma unroll 1
  for (int half = 0; half < 2; ++half) {
    int n0 = mBase + wv * 8 + half * 4;
    int nq = n0 + q; nq = nq < n ? nq : n - 1;   // quarter's node (clamped tail)
    int sreg[4];
#pragma unroll
    for (int b = 0; b < 4; ++b)      // transposed slot preload, in flight
      sreg[b] = (int)slot[(size_t)nq * PAD + b * 16 + c];
    int cq = cntp[nq]; cq = cq > PAD ? PAD : cq;
    int m1 = __shfl(cq, lane ^ 16, 64); int t1 = cq > m1 ? cq : m1;
    int m2 = __shfl(t1, lane ^ 32, 64); int tmax = t1 > m2 ? t1 : m2;  // batch max

    float A[8] = {0.f,0.f,0.f,0.f,0.f,0.f,0.f,0.f};
    uint4 sv = *(const uint4*)(xs + (size_t)nq * 64 + c * 4);   // self term
    acc8(A, sv);
#pragma unroll
    for (int b = 0; b < 4; ++b) {    // compile-time b: no dynamic sreg index
      if (b * 16 >= tmax) break;     // wave-uniform
      int jend = tmax - b * 16; jend = jend > 16 ? 16 : jend;
      int sr = sreg[b];
      for (int j = 0; j < jend; j += 4) {   // 4 x 1 KB loads in flight
        int s0 = __shfl(sr, qb + j + 0, 64);
        int s1 = __shfl(sr, qb + j + 1, 64);
        int s2 = __shfl(sr, qb + j + 2, 64);
        int s3 = __shfl(sr, qb + j + 3, 64);
        uint4 v0 = *(const uint4*)(xs + (size_t)s0 * 64 + c * 4);
        uint4 v1 = *(const uint4*)(xs + (size_t)s1 * 64 + c * 4);
        uint4 v2 = *(const uint4*)(xs + (size_t)s2 * 64 + c * 4);
        uint4 v3 = *(const uint4*)(xs + (size_t)s3 * 64 + c * 4);
        acc8(A, v0);
        acc8(A, v1);
        acc8(A, v2);
        acc8(A, v3);
      }
    }
    {
      float dd = dis[nq];
      u32 u[8];
#pragma unroll
      for (int k = 0; k < 8; ++k) { A[k] *= dd; u[k] = fbits(A[k]); }
      uint4 oh, ol;
      oh.x = (u[0] >> 16) | (u[1] & 0xffff0000u);
      oh.y = (u[2] >> 16) | (u[3] & 0xffff0000u);
      oh.z = (u[4] >> 16) | (u[5] & 0xffff0000u);
      oh.w = (u[6] >> 16) | (u[7] & 0xffff0000u);
      u32 l[8];
#pragma unroll
      for (int k = 0; k < 8; ++k) l[k] = fbits(A[k] - bfbits2f(u[k] >> 16));
      ol.x = (l[0] >> 16) | (l[1] & 0xffff0000u);
      ol.y = (l[2] >> 16) | (l[3] & 0xffff0000u);
      ol.z = (l[4] >> 16) | (l[5] & 0xffff0000u);
      ol.w = (l[6] >> 16) | (l[7] & 0xffff0000u);
      int lrow = wv * 8 + half * 4 + q;   // 0..63; garbage tail rows never read back
      *(uint4*)&lyh[lrow * LROW + c * 8] = oh;
      *(uint4*)&lyl[lrow * LROW + c * 8] = ol;
    }
  }
  __syncthreads();

  // ---- phase 2: GEMM, wave wv = col-tile wv (cols 16wv..16wv+15), 4 row-tiles ----
  bf16x8 Bh[4], Bl[4];
#pragma unroll
  for (int ks = 0; ks < 4; ++ks) {
    size_t boff = (size_t)(wv * 16 + r) * H + ks * 32 + q * 8;
    Bh[ks] = *(const bf16x8*)(Wh + boff);
    Bl[ks] = *(const bf16x8*)(Wl + boff);
  }
  float bv = bias[wv * 16 + r];
  int col0 = wv * 16 + r;
#pragma unroll
  for (int rt = 0; rt < 4; ++rt) {
    f32x4 acc = (f32x4){0.f, 0.f, 0.f, 0.f};
#pragma unroll
    for (int ks = 0; ks < 4; ++ks) {     // same 3-term hi/lo order as before
      int off = (rt * 16 + r) * LROW + ks * 32 + q * 8;
      bf16x8 Ah = *(const bf16x8*)&lyh[off];
      bf16x8 Al = *(const bf16x8*)&lyl[off];
      acc = __builtin_amdgcn_mfma_f32_16x16x32_bf16(Ah, Bh[ks], acc, 0, 0, 0);
      acc = __builtin_amdgcn_mfma_f32_16x16x32_bf16(Al, Bh[ks], acc, 0, 0, 0);
      acc = __builtin_amdgcn_mfma_f32_16x16x32_bf16(Ah, Bl[ks], acc, 0, 0, 0);
    }
#pragma unroll
    for (int g = 0; g < 4; ++g) {
      int row = mBase + rt * 16 + q * 4 + g;   // C/D: col=lane&15, row=q*4+reg
      if (row < n) {
        float v = acc[g] + bv;
        if (BF16OUT) {
          float dd = dis[row];
          ((u16*)outv)[(size_t)row * H + col0] = f2bf(dd * v);
        } else {
          ((float*)outv)[(size_t)row * H + col0] = v;
        }
      }
    }
  }
}

extern "C" void kernel_launch(void* const* d_in, const int* in_sizes, int n_in,
                              void* d_out, int out_size, void* d_ws, size_t ws_size,
                              hipStream_t stream) {
  const float* x0 = (const float*)d_in[0];
  const int*   ei = (const int*)d_in[1];
  const float* W1 = (const float*)d_in[2];
  const float* b1 = (const float*)d_in[3];
  const float* W2 = (const float*)d_in[4];
  const float* b2 = (const float*)d_in[5];
  int N = in_sizes[0] / H;
  int E = in_sizes[1] / 2;
  const int* srcA = ei;
  const int* dstA = ei + E;

  char* w = (char*)d_ws;
  auto alloc = [&](size_t bytes) -> void* {
    void* p = (void*)w; w += (bytes + 255) & ~(size_t)255; return p;
  };
  int*   cnt  = (int*)  alloc((size_t)N * 4);
  float* dis  = (float*)alloc((size_t)N * 4);
  u16*   slot = (u16*)  alloc((size_t)N * PAD * 2);
  u32*   xs   = (u32*)  alloc((size_t)(N + 1) * 64 * 4); // +1: dummy zero row N
  u32*   xs2  = (u32*)  alloc((size_t)(N + 1) * 64 * 4); // layer-2 in
  u16*   W1h  = (u16*)  alloc((size_t)H * H * 2);
  u16*   W1l  = (u16*)  alloc((size_t)H * H * 2);
  u16*   W2h  = (u16*)  alloc((size_t)H * H * 2);
  u16*   W2l  = (u16*)  alloc((size_t)H * H * 2);

  k_init   <<<(N + 255) / 256, 256, 0, stream>>>(cnt, N, W1, W1h, W1l, W2, W2h, W2l);
  k_scatter<<<(E + 255) / 256, 256, 0, stream>>>(srcA, dstA, cnt, slot, E, N);
  k_prep_x <<<(N + 4) / 4, 256, 0, stream>>>((const float2*)x0, cnt, dis, xs, xs2, slot, N);

  // Layer 1: xs2 = bf16(dis * (A~*xs @ W1^T + b1))
  k_layer<true><<<(N + MT - 1) / MT, 512, 0, stream>>>(
      xs, cnt, slot, dis, W1h, W1l, b1, (void*)xs2, N);
  // Layer 2: out = A~*xs2 @ W2^T + b2 (fp32)
  k_layer<false><<<(N + MT - 1) / MT, 512, 0, stream>>>(
      xs2, cnt, slot, dis, W2h, W2l, b2, d_out, N);
}

// Round 7
// 190.117 us; speedup vs baseline: 1.4540x; 1.0115x over previous
//
#include <hip/hip_runtime.h>

typedef unsigned short u16;
typedef unsigned int   u32;

#define H    128
#define PAD  64    // slot row length == wave width; rows fully N-padded
#define LROW 136   // LDS row stride in u16: 128 + 8 pad (272 B, 16B-aligned)
#define MT   64    // M-tile per block (64 nodes) -> 782 blocks, 8 waves, 8 nodes/wave
#define CSTR 16    // cnt stride in ints: one counter per 64 B line (atomic parallelism)

typedef __attribute__((ext_vector_type(8))) short bf16x8;
typedef __attribute__((ext_vector_type(4))) float f32x4;

__device__ __forceinline__ float bfbits2f(u32 bits16) {
  union { float f; u32 u; } c; c.u = bits16 << 16; return c.f;
}
__device__ __forceinline__ u16 f2bf(float f) {       // RNE
  union { float f; u32 u; } c; c.f = f;
  u32 u = c.u;
  return (u16)((u + 0x7fffu + ((u >> 16) & 1u)) >> 16);
}
__device__ __forceinline__ u32 fbits(float f) {
  union { float f; u32 u; } c; c.f = f; return c.u;
}

__device__ __forceinline__ void acc8(float* a, uint4 v) {
  a[0] += bfbits2f(v.x & 0xffffu); a[1] += bfbits2f(v.x >> 16);
  a[2] += bfbits2f(v.y & 0xffffu); a[3] += bfbits2f(v.y >> 16);
  a[4] += bfbits2f(v.z & 0xffffu); a[5] += bfbits2f(v.z >> 16);
  a[6] += bfbits2f(v.w & 0xffffu); a[7] += bfbits2f(v.w >> 16);
}

// cnt zero (line-padded: N*CSTR ints) + both W hi/lo splits in one launch.
__global__ void k_init(int* __restrict__ cnt, int N,
                       const float* __restrict__ W1, u16* __restrict__ W1h, u16* __restrict__ W1l,
                       const float* __restrict__ W2, u16* __restrict__ W2h, u16* __restrict__ W2l) {
  int i = blockIdx.x * blockDim.x + threadIdx.x;
  if (i < N * CSTR) cnt[i] = 0;
  if (i < H * H) {
    float w1 = W1[i];
    u16 h1 = f2bf(w1);
    W1h[i] = h1; W1l[i] = f2bf(w1 - bfbits2f(h1));
    float w2 = W2[i];
    u16 h2 = f2bf(w2);
    W2h[i] = h2; W2l[i] = f2bf(w2 - bfbits2f(h2));
  }
}

// slot[d*PAD + pos] = src (u16). cnt[d*CSTR] ends as true in-degree.
// Counters line-padded (CSTR) so same-line atomic serialization at the
// coherence point is eliminated (was 16 counters -> ~192 atomics per line).
__global__ void k_scatter(const int* __restrict__ srcA, const int* __restrict__ dstA,
                          int* __restrict__ cnt, u16* __restrict__ slot, int E, int N) {
  int e = blockIdx.x * blockDim.x + threadIdx.x;
  if (e < E) {
    int s = srcA[e], d = dstA[e];
    s = s < 0 ? 0 : (s >= N ? N - 1 : s);
    d = d < 0 ? 0 : (d >= N ? N - 1 : d);
    int pos = atomicAdd(&cnt[d * CSTR], 1);
    if (pos < PAD) slot[(size_t)d * PAD + pos] = (u16)s;
  }
}

// Per node: dis = rsqrt(deg+1); xs = bf16(dis*x) interleaved [node][64 u32];
// slot row fully padded with dummy index n (zero row). Node n: zero rows of
// xs AND xs2 (layer-2 dummy).
__global__ __launch_bounds__(256) void k_prep_x(
    const float2* __restrict__ x, const int* __restrict__ cnt,
    float* __restrict__ dis, u32* __restrict__ xs, u32* __restrict__ xs2,
    u16* __restrict__ slot, int n) {
  int lane = threadIdx.x & 63;
  int node = blockIdx.x * 4 + (threadIdx.x >> 6);
  if (node > n) return;
  if (node == n) {                   // dummy zero rows for padded gathers
    xs [(size_t)n * 64 + lane] = 0u;
    xs2[(size_t)n * 64 + lane] = 0u;
    return;
  }
  int cv = cnt[node * CSTR];
  float d = rsqrtf((float)(cv + 1));
  if (lane == 0) dis[node] = d;
  float2 v = x[(size_t)node * 64 + lane];
  xs[(size_t)node * 64 + lane] = (u32)f2bf(d * v.x) | ((u32)f2bf(d * v.y) << 16);
  int cc = cv > PAD ? PAD : cv;
  if (lane >= cc) slot[(size_t)node * PAD + lane] = (u16)n;  // full N-pad
}

// Fused layer, MT=64 nodes/block (512 thr, 8 waves), 8 nodes/wave processed
// as TWO sequential 4-node batches (per-batch math identical to the MT=32
// version -> bit-identical output). QUARTER-OWNS-NODE: 16-lane quarter q owns
// one node entirely (16 lanes x uint4 = full 256 B row). One load instruction
// = 4 rows (1 KB), 4 nodes in parallel, ZERO cross-lane reduction. Slot rows
// preloaded transposed; edge loop flat + unconditional (rows fully N-padded;
// trip = max deg of the batch's 4 nodes), 4 x 1 KB loads in flight (8-deep
// uint4 spilled — round-3 lesson).
// Phase 2: 64x128 @ 128x128 GEMM; wave wv owns a 16-col x 64-row slice so
// each W fragment set (4 hi + 4 lo, 8 KB/wave) is reused across FOUR
// row-tiles — W traffic per layer = (N/64)*64KB = 50 MB. A-frags loaded
// per-ks inside the MFMA loop (64-VGPR cap). Same 3-term hi/lo MFMA order
// as before (bit-identical output).
// BF16OUT: out = bf16(dis * (y@W^T+b)) for next layer.
template <bool BF16OUT>
__global__ __launch_bounds__(512, 8) void k_layer(
    const u32* __restrict__ xs, const int* __restrict__ cntp,
    const u16* __restrict__ slot, const float* __restrict__ dis,
    const u16* __restrict__ Wh, const u16* __restrict__ Wl,
    const float* __restrict__ bias, void* __restrict__ outv, int n) {
  __shared__ u16 lyh[MT * LROW];
  __shared__ u16 lyl[MT * LROW];
  int wv = threadIdx.x >> 6;         // 0..7
  int lane = threadIdx.x & 63;
  int mBase = blockIdx.x * MT;
  int r = lane & 15, q = lane >> 4;
  int qb = lane & 48;                // quarter base lane
  int c  = r;                        // feature group [8c, 8c+8)

  // ---- phase 1: two 4-node batches per wave ----
#pragma unroll 1
  for (int half = 0; half < 2; ++half) {
    int n0 = mBase + wv * 8 + half * 4;
    int nq = n0 + q; nq = nq < n ? nq : n - 1;   // quarter's node (clamped tail)
    int sreg[4];
#pragma unroll
    for (int b = 0; b < 4; ++b)      // transposed slot preload, in flight
      sreg[b] = (int)slot[(size_t)nq * PAD + b * 16 + c];
    int cq = cntp[nq * CSTR]; cq = cq > PAD ? PAD : cq;
    int m1 = __shfl(cq, lane ^ 16, 64); int t1 = cq > m1 ? cq : m1;
    int m2 = __shfl(t1, lane ^ 32, 64); int tmax = t1 > m2 ? t1 : m2;  // batch max

    float A[8] = {0.f,0.f,0.f,0.f,0.f,0.f,0.f,0.f};
    uint4 sv = *(const uint4*)(xs + (size_t)nq * 64 + c * 4);   // self term
    acc8(A, sv);
#pragma unroll
    for (int b = 0; b < 4; ++b) {    // compile-time b: no dynamic sreg index
      if (b * 16 >= tmax) break;     // wave-uniform
      int jend = tmax - b * 16; jend = jend > 16 ? 16 : jend;
      int sr = sreg[b];
      for (int j = 0; j < jend; j += 4) {   // 4 x 1 KB loads in flight
        int s0 = __shfl(sr, qb + j + 0, 64);
        int s1 = __shfl(sr, qb + j + 1, 64);
        int s2 = __shfl(sr, qb + j + 2, 64);
        int s3 = __shfl(sr, qb + j + 3, 64);
        uint4 v0 = *(const uint4*)(xs + (size_t)s0 * 64 + c * 4);
        uint4 v1 = *(const uint4*)(xs + (size_t)s1 * 64 + c * 4);
        uint4 v2 = *(const uint4*)(xs + (size_t)s2 * 64 + c * 4);
        uint4 v3 = *(const uint4*)(xs + (size_t)s3 * 64 + c * 4);
        acc8(A, v0);
        acc8(A, v1);
        acc8(A, v2);
        acc8(A, v3);
      }
    }
    {
      float dd = dis[nq];
      u32 u[8];
#pragma unroll
      for (int k = 0; k < 8; ++k) { A[k] *= dd; u[k] = fbits(A[k]); }
      uint4 oh, ol;
      oh.x = (u[0] >> 16) | (u[1] & 0xffff0000u);
      oh.y = (u[2] >> 16) | (u[3] & 0xffff0000u);
      oh.z = (u[4] >> 16) | (u[5] & 0xffff0000u);
      oh.w = (u[6] >> 16) | (u[7] & 0xffff0000u);
      u32 l[8];
#pragma unroll
      for (int k = 0; k < 8; ++k) l[k] = fbits(A[k] - bfbits2f(u[k] >> 16));
      ol.x = (l[0] >> 16) | (l[1] & 0xffff0000u);
      ol.y = (l[2] >> 16) | (l[3] & 0xffff0000u);
      ol.z = (l[4] >> 16) | (l[5] & 0xffff0000u);
      ol.w = (l[6] >> 16) | (l[7] & 0xffff0000u);
      int lrow = wv * 8 + half * 4 + q;   // 0..63; garbage tail rows never read back
      *(uint4*)&lyh[lrow * LROW + c * 8] = oh;
      *(uint4*)&lyl[lrow * LROW + c * 8] = ol;
    }
  }
  __syncthreads();

  // ---- phase 2: GEMM, wave wv = col-tile wv (cols 16wv..16wv+15), 4 row-tiles ----
  bf16x8 Bh[4], Bl[4];
#pragma unroll
  for (int ks = 0; ks < 4; ++ks) {
    size_t boff = (size_t)(wv * 16 + r) * H + ks * 32 + q * 8;
    Bh[ks] = *(const bf16x8*)(Wh + boff);
    Bl[ks] = *(const bf16x8*)(Wl + boff);
  }
  float bv = bias[wv * 16 + r];
  int col0 = wv * 16 + r;
#pragma unroll
  for (int rt = 0; rt < 4; ++rt) {
    f32x4 acc = (f32x4){0.f, 0.f, 0.f, 0.f};
#pragma unroll
    for (int ks = 0; ks < 4; ++ks) {     // same 3-term hi/lo order as before
      int off = (rt * 16 + r) * LROW + ks * 32 + q * 8;
      bf16x8 Ah = *(const bf16x8*)&lyh[off];
      bf16x8 Al = *(const bf16x8*)&lyl[off];
      acc = __builtin_amdgcn_mfma_f32_16x16x32_bf16(Ah, Bh[ks], acc, 0, 0, 0);
      acc = __builtin_amdgcn_mfma_f32_16x16x32_bf16(Al, Bh[ks], acc, 0, 0, 0);
      acc = __builtin_amdgcn_mfma_f32_16x16x32_bf16(Ah, Bl[ks], acc, 0, 0, 0);
    }
#pragma unroll
    for (int g = 0; g < 4; ++g) {
      int row = mBase + rt * 16 + q * 4 + g;   // C/D: col=lane&15, row=q*4+reg
      if (row < n) {
        float v = acc[g] + bv;
        if (BF16OUT) {
          float dd = dis[row];
          ((u16*)outv)[(size_t)row * H + col0] = f2bf(dd * v);
        } else {
          ((float*)outv)[(size_t)row * H + col0] = v;
        }
      }
    }
  }
}

extern "C" void kernel_launch(void* const* d_in, const int* in_sizes, int n_in,
                              void* d_out, int out_size, void* d_ws, size_t ws_size,
                              hipStream_t stream) {
  const float* x0 = (const float*)d_in[0];
  const int*   ei = (const int*)d_in[1];
  const float* W1 = (const float*)d_in[2];
  const float* b1 = (const float*)d_in[3];
  const float* W2 = (const float*)d_in[4];
  const float* b2 = (const float*)d_in[5];
  int N = in_sizes[0] / H;
  int E = in_sizes[1] / 2;
  const int* srcA = ei;
  const int* dstA = ei + E;

  char* w = (char*)d_ws;
  auto alloc = [&](size_t bytes) -> void* {
    void* p = (void*)w; w += (bytes + 255) & ~(size_t)255; return p;
  };
  int*   cnt  = (int*)  alloc((size_t)N * CSTR * 4);  // line-padded counters
  float* dis  = (float*)alloc((size_t)N * 4);
  u16*   slot = (u16*)  alloc((size_t)N * PAD * 2);
  u32*   xs   = (u32*)  alloc((size_t)(N + 1) * 64 * 4); // +1: dummy zero row N
  u32*   xs2  = (u32*)  alloc((size_t)(N + 1) * 64 * 4); // layer-2 in
  u16*   W1h  = (u16*)  alloc((size_t)H * H * 2);
  u16*   W1l  = (u16*)  alloc((size_t)H * H * 2);
  u16*   W2h  = (u16*)  alloc((size_t)H * H * 2);
  u16*   W2l  = (u16*)  alloc((size_t)H * H * 2);

  k_init   <<<(N * CSTR + 255) / 256, 256, 0, stream>>>(cnt, N, W1, W1h, W1l, W2, W2h, W2l);
  k_scatter<<<(E + 255) / 256, 256, 0, stream>>>(srcA, dstA, cnt, slot, E, N);
  k_prep_x <<<(N + 4) / 4, 256, 0, stream>>>((const float2*)x0, cnt, dis, xs, xs2, slot, N);

  // Layer 1: xs2 = bf16(dis * (A~*xs @ W1^T + b1))
  k_layer<true><<<(N + MT - 1) / MT, 512, 0, stream>>>(
      xs, cnt, slot, dis, W1h, W1l, b1, (void*)xs2, N);
  // Layer 2: out = A~*xs2 @ W2^T + b2 (fp32)
  k_layer<false><<<(N + MT - 1) / MT, 512, 0, stream>>>(
      xs2, cnt, slot, dis, W2h, W2l, b2, d_out, N);
}